// Round 14
// baseline (403.015 us; speedup 1.0000x reference)
//
#include <hip/hip_runtime.h>
#include <hip/hip_fp16.h>
#include <math.h>

constexpr int B  = 4;
constexpr int S  = 12;
constexpr int N  = 20000;
constexpr int HD = 64;
constexpr int E0 = 640000;
constexpr int EL = E0 + N;      // edges + self loops
constexpr int BN = B * N;
constexpr int CAP = 128;        // padded CSR bucket capacity (deg: mean 32, sd 5.7)

// ---------------- padded-bucket CSR build: one kernel, no scan ---------------
__global__ void scatter_kernel(const int* __restrict__ ei, int* __restrict__ cnt,
                               int* __restrict__ perm) {
    int e = blockIdx.x * blockDim.x + threadIdx.x;
    if (e >= EL) return;
    int s, d;
    if (e < E0) { s = ei[e]; d = ei[E0 + e]; }
    else        { s = e - E0; d = s; }
    int pos = atomicAdd(&cnt[d], 1) & (CAP - 1);   // mask: can't corrupt neighbors
    perm[d * CAP + pos] = s;
}

// ---- conv weight transpose: cwD[dt*4096 + c*64 + o] = cw[o*192 + c*3 + dt] --
__global__ void tw_kernel(const float* __restrict__ cw, float* __restrict__ cwD) {
    int i = blockIdx.x * blockDim.x + threadIdx.x;
    if (i >= HD * HD * 3) return;
    int o = i / (HD * 3), rem = i % (HD * 3), c = rem / 3, dt = rem % 3;
    cwD[dt * (HD * HD) + c * HD + o] = cw[i];
}

// ======== gemm family v3 + v16: hidden state fp16 end-to-end ================
constexpr int GT = 64;                  // nodes per block (4 waves x 16)

template<int H>
__global__ __launch_bounds__(256, 4)
void gemm_attn_kernel(const float* __restrict__ hin, const float* __restrict__ w,
                      const float* __restrict__ asrc, const float* __restrict__ adst,
                      float* __restrict__ xe, float* __restrict__ es, float* __restrict__ ed) {
    __shared__ __half tileh[GT * HD];   // 8KB
    int base = blockIdx.x * GT;
    const float4* src4 = (const float4*)((const __half*)hin + (size_t)base * HD);
    for (int i = threadIdx.x; i < GT * HD / 8; i += 256)   // 512 x 16B
        ((float4*)tileh)[i] = src4[i];
    int lane = threadIdx.x & 63;
    float wres[HD];                     // w[c][lane], c compile-time -> VGPRs
    #pragma unroll
    for (int c = 0; c < HD; ++c) wres[c] = w[c * HD + lane];
    float as_ = asrc[lane], ad_ = adst[lane];
    __syncthreads();
    int wvid = threadIdx.x >> 6;
    for (int j = wvid * 16; j < wvid * 16 + 16; ++j) {
        int t = base + j;
        float acc = 0.f;
        #pragma unroll
        for (int q = 0; q < 8; ++q) {
            float4 raw = ((const float4*)tileh)[j * 8 + q];  // 8 halves broadcast
            const __half2* hp = (const __half2*)&raw;
            float2 v0 = __half22float2(hp[0]);
            float2 v1 = __half22float2(hp[1]);
            float2 v2 = __half22float2(hp[2]);
            float2 v3 = __half22float2(hp[3]);
            acc = fmaf(v0.x, wres[8*q+0], acc);
            acc = fmaf(v0.y, wres[8*q+1], acc);
            acc = fmaf(v1.x, wres[8*q+2], acc);
            acc = fmaf(v1.y, wres[8*q+3], acc);
            acc = fmaf(v2.x, wres[8*q+4], acc);
            acc = fmaf(v2.y, wres[8*q+5], acc);
            acc = fmaf(v3.x, wres[8*q+6], acc);
            acc = fmaf(v3.y, wres[8*q+7], acc);
        }
        ((__half*)xe)[(size_t)t * HD + lane] = __float2half(acc);   // coalesced 128B
        float t0 = acc * as_, t1 = acc * ad_;
        if (H == 8) {
            #pragma unroll
            for (int m = 1; m < 8; m <<= 1) {
                t0 += __shfl_xor(t0, m, 64);
                t1 += __shfl_xor(t1, m, 64);
            }
            if ((lane & 7) == 0) {
                es[t * 8 + (lane >> 3)] = t0;
                ed[t * 8 + (lane >> 3)] = t1;
            }
        } else {
            #pragma unroll
            for (int m = 1; m < 64; m <<= 1) {
                t0 += __shfl_xor(t0, m, 64);
                t1 += __shfl_xor(t1, m, 64);
            }
            if (lane == 0) { es[t] = t0; ed[t] = t1; }
        }
    }
}

// layer 0: proj fused in. h row computed per-lane, broadcast via fp16 LDS row.
__global__ __launch_bounds__(256, 4)
void fused0_kernel(const float* __restrict__ x, const float* __restrict__ pw,
                   const float* __restrict__ pb, const float* __restrict__ w,
                   const float* __restrict__ asrc, const float* __restrict__ adst,
                   float* __restrict__ xe, float* __restrict__ es, float* __restrict__ ed) {
    __shared__ __half tileh[GT * HD];   // 8KB
    __shared__ float xt[S * GT];
    int base = blockIdx.x * GT;
    for (int i = threadIdx.x; i < S * GT; i += 256) {
        int s = i >> 6, nl = i & 63;
        int t = base + nl, bb = t / N, n = t - bb * N;
        xt[i] = x[(bb * S + s) * N + n];          // coalesced per s-segment
    }
    int lane = threadIdx.x & 63;
    float wres[HD];
    #pragma unroll
    for (int c = 0; c < HD; ++c) wres[c] = w[c * HD + lane];
    float pwres[S];
    #pragma unroll
    for (int s = 0; s < S; ++s) pwres[s] = pw[s * HD + lane];
    float pbv = pb[lane];
    float as_ = asrc[lane], ad_ = adst[lane];
    __syncthreads();
    int wvid = threadIdx.x >> 6;
    // phase A: this wave's 16 h-rows (lane = channel), written to tile fp16
    for (int j = wvid * 16; j < wvid * 16 + 16; ++j) {
        float hl = pbv;
        #pragma unroll
        for (int s = 0; s < S; ++s)
            hl = fmaf(xt[s * GT + j], pwres[s], hl);         // broadcast read
        tileh[j * HD + lane] = __float2half(hl);             // own wave's row
    }
    // phase B: gemm + attn (reads only this wave's rows -> no barrier needed)
    for (int j = wvid * 16; j < wvid * 16 + 16; ++j) {
        int t = base + j;
        float acc = 0.f;
        #pragma unroll
        for (int q = 0; q < 8; ++q) {
            float4 raw = ((const float4*)tileh)[j * 8 + q];
            const __half2* hp = (const __half2*)&raw;
            float2 v0 = __half22float2(hp[0]);
            float2 v1 = __half22float2(hp[1]);
            float2 v2 = __half22float2(hp[2]);
            float2 v3 = __half22float2(hp[3]);
            acc = fmaf(v0.x, wres[8*q+0], acc);
            acc = fmaf(v0.y, wres[8*q+1], acc);
            acc = fmaf(v1.x, wres[8*q+2], acc);
            acc = fmaf(v1.y, wres[8*q+3], acc);
            acc = fmaf(v2.x, wres[8*q+4], acc);
            acc = fmaf(v2.y, wres[8*q+5], acc);
            acc = fmaf(v3.x, wres[8*q+6], acc);
            acc = fmaf(v3.y, wres[8*q+7], acc);
        }
        ((__half*)xe)[(size_t)t * HD + lane] = __float2half(acc);
        float t0 = acc * as_, t1 = acc * ad_;
        #pragma unroll
        for (int m = 1; m < 8; m <<= 1) {
            t0 += __shfl_xor(t0, m, 64);
            t1 += __shfl_xor(t1, m, 64);
        }
        if ((lane & 7) == 0) {
            es[t * 8 + (lane >> 3)] = t0;
            ed[t * 8 + (lane >> 3)] = t1;
        }
    }
}

// ------- fused aggregation v17: 8 groups x 8 lanes — 2x edges in flight -----
// Confirmed −16us (R12). 32 edges in flight/wave ≈ mean degree: MLP saturated.
template<int H, bool DO_ELU, bool OUT_HALF>
__global__ __launch_bounds__(256, 8)
void agg_kernel(const float* __restrict__ xe, const float* __restrict__ es,
                const float* __restrict__ ed, const int* __restrict__ cnt,
                const int* __restrict__ perm, const float* __restrict__ bias,
                float* __restrict__ hout) {
    int g = blockIdx.x;                       // 20000 blocks, multiple of 8
    int bb   = (g & 7) >> 1;                  // batch from XCD pair
    int idx  = (g >> 3) * 2 + (g & 1);        // 0..4999 within batch
    int node = idx * 4 + (threadIdx.x >> 6);  // < 20000
    int lane  = threadIdx.x & 63;
    int group = lane >> 3;                    // 0..7: owns an edge
    int c8    = lane & 7;                     // head (H=8) / channel octet
    int deg = cnt[node];
    int baseE = node * CAP;
    int h = (H == 8) ? c8 : 0;
    const float*  es_b = es + bb * (N * H);
    const __half* xeh  = (const __half*)xe + (size_t)bb * N * HD;
    float edv = ed[(bb * N + node) * H + h];
    float acc[8] = {0.f,0.f,0.f,0.f,0.f,0.f,0.f,0.f};
    float ssum = 0.f;
    #pragma unroll 4
    for (int jb = 0; jb < deg; jb += 8) {
        int j = jb + group;
        bool valid = (j < deg);
        int src = perm[baseE + (valid ? j : 0)];     // slot 0 always exists
        float e = es_b[src * H + h] + edv;
        e = fmaxf(e, 0.2f * e);                      // leaky_relu(0.2)
        float p = valid ? __expf(e) : 0.f;
        ssum += p;
        float4 raw = *(const float4*)(xeh + (size_t)src * HD + c8 * 8);  // 16B
        const __half2* hp2 = (const __half2*)&raw;
        float2 v0 = __half22float2(hp2[0]);
        float2 v1 = __half22float2(hp2[1]);
        float2 v2 = __half22float2(hp2[2]);
        float2 v3 = __half22float2(hp2[3]);
        acc[0] = fmaf(p, v0.x, acc[0]);
        acc[1] = fmaf(p, v0.y, acc[1]);
        acc[2] = fmaf(p, v1.x, acc[2]);
        acc[3] = fmaf(p, v1.y, acc[3]);
        acc[4] = fmaf(p, v2.x, acc[4]);
        acc[5] = fmaf(p, v2.y, acc[5]);
        acc[6] = fmaf(p, v3.x, acc[6]);
        acc[7] = fmaf(p, v3.y, acc[7]);
    }
    #pragma unroll
    for (int m = 8; m < 64; m <<= 1) {
        #pragma unroll
        for (int k = 0; k < 8; ++k) acc[k] += __shfl_xor(acc[k], m, 64);
        ssum += __shfl_xor(ssum, m, 64);
    }
    if (lane < 8) {                     // lane = c8: owns channels c8*8..+7
        float inv = 1.f / ssum;
        const float4* b4 = (const float4*)bias;
        float4 b0 = b4[c8 * 2 + 0], b1 = b4[c8 * 2 + 1];
        float r[8];
        r[0] = acc[0] * inv + b0.x; r[1] = acc[1] * inv + b0.y;
        r[2] = acc[2] * inv + b0.z; r[3] = acc[3] * inv + b0.w;
        r[4] = acc[4] * inv + b1.x; r[5] = acc[5] * inv + b1.y;
        r[6] = acc[6] * inv + b1.z; r[7] = acc[7] * inv + b1.w;
        if (DO_ELU) {
            #pragma unroll
            for (int k = 0; k < 8; ++k)
                r[k] = (r[k] > 0.f) ? r[k] : expm1f(r[k]);
        }
        if (OUT_HALF) {
            union { __half2 h2[4]; float4 f4; } u;
            u.h2[0] = __floats2half2_rn(r[0], r[1]);
            u.h2[1] = __floats2half2_rn(r[2], r[3]);
            u.h2[2] = __floats2half2_rn(r[4], r[5]);
            u.h2[3] = __floats2half2_rn(r[6], r[7]);
            ((float4*)hout)[(size_t)(bb * N + node) * 8 + c8] = u.f4;   // 16B
        } else {
            float4 lo = {r[0], r[1], r[2], r[3]};
            float4 hi = {r[4], r[5], r[6], r[7]};
            float4* o4 = (float4*)hout + (size_t)(bb * N + node) * 16 + c8 * 2;
            o4[0] = lo;
            o4[1] = hi;
        }
    }
}

// ======== conv v19: row-reuse — each fp16 row s_loaded ONCE =================
// v18 (fp16 rows) cut FETCH 2x and dur 67.5->59.7, but SGPR 64 shows ~1 row
// in flight: 96 row-load events/wave, each a serialized L2 round-trip, remain
// the limiter. v19 inverts the loops: iterate 18 rows (incl. halo) once per
// ch-half, s_load each half-row ONCE (16 dwords = 1x s_load_dwordx16), and
// scatter its 3 dt-contributions into wp[rr], wp[rr-1], wp[rr-2] with all 3
// weight sets resident (w0/w1/w2 = 96 VGPR, static idx). Row-load events
// 96 -> 36 (2.7x fewer stalls). Accumulators stay in LDS wp (proven RMW path
// since v7.1 — avoids v10's scratch trap). launch_bounds(128,2) unchanged.
// Health: WRITE_SIZE must stay 937KB (growth = spill).
constexpr int CVN = 16;                 // nodes per wave
__global__ __launch_bounds__(128, 2)
void conv_out_kernel(const float* __restrict__ h, const float* __restrict__ cwD,
                     const float* __restrict__ cb, const float* __restrict__ ow,
                     const float* __restrict__ ob, float* __restrict__ out) {
    __shared__ float part[2 * CVN * HD];   // 8KB, wave-private halves
    int bb = blockIdx.y;
    int wvid = __builtin_amdgcn_readfirstlane(threadIdx.x >> 6);  // SGPR: 0..1
    int base = blockIdx.x * (2 * CVN) + wvid * CVN;   // scalar; N = 625*32
    int lane = threadIdx.x & 63;           // = output channel o
    float* wp = part + wvid * (CVN * HD);  // this wave's 4KB slice (scalar base)
    const __half* hb = (const __half*)h;   // fp16 rows from agg2
    float cbv = cb[lane];
    float ow0 = ow[lane * 3 + 0], ow1 = ow[lane * 3 + 1], ow2 = ow[lane * 3 + 2];
    float ob0 = ob[0], ob1 = ob[1], ob2 = ob[2];
    #pragma unroll
    for (int j = 0; j < CVN; ++j) wp[j * HD + lane] = cbv;
    #pragma unroll 1
    for (int ch = 0; ch < 2; ++ch) {       // channel halves: wres 3x32 VGPR
        float w0[32], w1[32], w2[32];
        #pragma unroll
        for (int c = 0; c < 32; ++c) {
            w0[c] = cwD[0 * (HD * HD) + (ch * 32 + c) * HD + lane];
            w1[c] = cwD[1 * (HD * HD) + (ch * 32 + c) * HD + lane];
            w2[c] = cwD[2 * (HD * HD) + (ch * 32 + c) * HD + lane];
        }
        #pragma unroll
        for (int rr = 0; rr < CVN + 2; ++rr) {       // row = node base+rr-1
            int m = base + rr - 1;
            if (m >= 0 && m < N) {      // uniform branch (s_cbranch)
                const unsigned int* hpu =
                    (const unsigned int*)(hb + ((size_t)bb * N + m) * HD + ch * 32);
                float vf[32];            // unpacked row half (static idx)
                #pragma unroll
                for (int c2 = 0; c2 < 16; ++c2) {
                    unsigned int wbits = hpu[c2];        // s_load (1x dwordx16)
                    __half2 h2 = *(const __half2*)&wbits;
                    float2 f = __half22float2(h2);
                    vf[2 * c2 + 0] = f.x;
                    vf[2 * c2 + 1] = f.y;
                }
                if (rr <= CVN - 1) {                 // dt=0 -> out rr
                    float a = 0.f;
                    #pragma unroll
                    for (int c = 0; c < 32; ++c) a = fmaf(vf[c], w0[c], a);
                    wp[rr * HD + lane] += a;
                }
                if (rr >= 1 && rr <= CVN) {          // dt=1 -> out rr-1
                    float a = 0.f;
                    #pragma unroll
                    for (int c = 0; c < 32; ++c) a = fmaf(vf[c], w1[c], a);
                    wp[(rr - 1) * HD + lane] += a;
                }
                if (rr >= 2) {                       // dt=2 -> out rr-2
                    float a = 0.f;
                    #pragma unroll
                    for (int c = 0; c < 32; ++c) a = fmaf(vf[c], w2[c], a);
                    wp[(rr - 2) * HD + lane] += a;
                }
            }
        }
    }
    // epilogue: relu + 64->3 via butterfly
    #pragma unroll 1
    for (int j = 0; j < CVN; ++j) {
        float v = fmaxf(wp[j * HD + lane], 0.f);
        float t0 = v * ow0, t1 = v * ow1, t2 = v * ow2;
        #pragma unroll
        for (int m = 1; m < 64; m <<= 1) {
            t0 += __shfl_xor(t0, m, 64);
            t1 += __shfl_xor(t1, m, 64);
            t2 += __shfl_xor(t2, m, 64);
        }
        int n = base + j;               // always < N (625*32 = 20000)
        if (lane < 3) {
            float r = (lane == 0) ? t0 + ob0 : (lane == 1) ? t1 + ob1 : t2 + ob2;
            out[(size_t)bb * 3 * N + lane * N + n] = r;
        }
    }
}

extern "C" void kernel_launch(void* const* d_in, const int* in_sizes, int n_in,
                              void* d_out, int out_size, void* d_ws, size_t ws_size,
                              hipStream_t stream) {
    const float* x      = (const float*)d_in[0];
    const int*   ei     = (const int*)  d_in[1];
    const float* proj_w = (const float*)d_in[2];
    const float* proj_b = (const float*)d_in[3];
    const float* g_w [3] = {(const float*)d_in[4], (const float*)d_in[8],  (const float*)d_in[12]};
    const float* g_as[3] = {(const float*)d_in[5], (const float*)d_in[9],  (const float*)d_in[13]};
    const float* g_ad[3] = {(const float*)d_in[6], (const float*)d_in[10], (const float*)d_in[14]};
    const float* g_b [3] = {(const float*)d_in[7], (const float*)d_in[11], (const float*)d_in[15]};
    const float* conv_w = (const float*)d_in[16];
    const float* conv_b = (const float*)d_in[17];
    const float* out_w  = (const float*)d_in[18];
    const float* out_b  = (const float*)d_in[19];
    float* out = (float*)d_out;

    // workspace layout (fp32-sized regions; bufX = fp16 xe; bufA = fp16
    // hidden state everywhere now, incl. conv input)
    float* bufA = (float*)d_ws;                      // BN*HD
    float* bufX = bufA + (size_t)BN * HD;            // BN*HD
    float* es   = bufX + (size_t)BN * HD;            // BN*8 (max H)
    float* ed   = es   + (size_t)BN * 8;             // BN*8
    int* cnt  = (int*)(ed + (size_t)BN * 8);         // N
    int* perm = cnt + N;                             // N*CAP
    float* cwD = (float*)(perm + (size_t)N * CAP);   // 3*64*64

    const int TB = 256;
    const int gE = (EL + TB - 1) / TB;

    // CSR build: memset + single scatter (padded buckets, no scan)
    hipMemsetAsync(cnt, 0, N * sizeof(int), stream);
    scatter_kernel<<<gE, TB, 0, stream>>>(ei, cnt, perm);

    // conv weight transpose to [dt][c][o]
    tw_kernel<<<(HD * HD * 3 + TB - 1) / TB, TB, 0, stream>>>(conv_w, cwD);

    // layer 0: proj + gemm + attn fused (reads x directly)
    fused0_kernel<<<BN / GT, TB, 0, stream>>>(x, proj_w, proj_b, g_w[0], g_as[0], g_ad[0],
                                              bufX, es, ed);
    agg_kernel<8, true, true><<<BN / 4, TB, 0, stream>>>(bufX, es, ed, cnt, perm, g_b[0], bufA);

    // layer 1 (H=8) + ELU; hin fp16
    gemm_attn_kernel<8><<<BN / GT, TB, 0, stream>>>(bufA, g_w[1], g_as[1], g_ad[1], bufX, es, ed);
    agg_kernel<8, true, true><<<BN / 4, TB, 0, stream>>>(bufX, es, ed, cnt, perm, g_b[1], bufA);

    // layer 2 (H=1), no ELU; hin fp16, hout fp16 (conv reads fp16 rows)
    gemm_attn_kernel<1><<<BN / GT, TB, 0, stream>>>(bufA, g_w[2], g_as[2], g_ad[2], bufX, es, ed);
    agg_kernel<1, false, true><<<BN / 4, TB, 0, stream>>>(bufX, es, ed, cnt, perm, g_b[2], bufA);

    // conv1d(k=3) + relu + final projection, writes [B,3,N]
    conv_out_kernel<<<dim3(N / (2 * CVN), B), 128, 0, stream>>>(bufA, cwD, conv_b, out_w, out_b, out);
}

// Round 15
// 399.832 us; speedup vs baseline: 1.0080x; 1.0080x over previous
//
#include <hip/hip_runtime.h>
#include <hip/hip_fp16.h>
#include <math.h>

constexpr int B  = 4;
constexpr int S  = 12;
constexpr int N  = 20000;
constexpr int HD = 64;
constexpr int E0 = 640000;
constexpr int EL = E0 + N;      // edges + self loops
constexpr int BN = B * N;
constexpr int CAP = 128;        // padded CSR bucket capacity (deg: mean 32, sd 5.7)

// ---------------- padded-bucket CSR build: one kernel, no scan ---------------
__global__ void scatter_kernel(const int* __restrict__ ei, int* __restrict__ cnt,
                               int* __restrict__ perm) {
    int e = blockIdx.x * blockDim.x + threadIdx.x;
    if (e >= EL) return;
    int s, d;
    if (e < E0) { s = ei[e]; d = ei[E0 + e]; }
    else        { s = e - E0; d = s; }
    int pos = atomicAdd(&cnt[d], 1) & (CAP - 1);   // mask: can't corrupt neighbors
    perm[d * CAP + pos] = s;
}

// ---- conv weight transpose: cwD[dt*4096 + c*64 + o] = cw[o*192 + c*3 + dt] --
__global__ void tw_kernel(const float* __restrict__ cw, float* __restrict__ cwD) {
    int i = blockIdx.x * blockDim.x + threadIdx.x;
    if (i >= HD * HD * 3) return;
    int o = i / (HD * 3), rem = i % (HD * 3), c = rem / 3, dt = rem % 3;
    cwD[dt * (HD * HD) + c * HD + o] = cw[i];
}

// ======== gemm family v3 + v16: hidden state fp16 end-to-end ================
constexpr int GT = 64;                  // nodes per block (4 waves x 16)

template<int H>
__global__ __launch_bounds__(256, 4)
void gemm_attn_kernel(const float* __restrict__ hin, const float* __restrict__ w,
                      const float* __restrict__ asrc, const float* __restrict__ adst,
                      float* __restrict__ xe, float* __restrict__ es, float* __restrict__ ed) {
    __shared__ __half tileh[GT * HD];   // 8KB
    int base = blockIdx.x * GT;
    const float4* src4 = (const float4*)((const __half*)hin + (size_t)base * HD);
    for (int i = threadIdx.x; i < GT * HD / 8; i += 256)   // 512 x 16B
        ((float4*)tileh)[i] = src4[i];
    int lane = threadIdx.x & 63;
    float wres[HD];                     // w[c][lane], c compile-time -> VGPRs
    #pragma unroll
    for (int c = 0; c < HD; ++c) wres[c] = w[c * HD + lane];
    float as_ = asrc[lane], ad_ = adst[lane];
    __syncthreads();
    int wvid = threadIdx.x >> 6;
    for (int j = wvid * 16; j < wvid * 16 + 16; ++j) {
        int t = base + j;
        float acc = 0.f;
        #pragma unroll
        for (int q = 0; q < 8; ++q) {
            float4 raw = ((const float4*)tileh)[j * 8 + q];  // 8 halves broadcast
            const __half2* hp = (const __half2*)&raw;
            float2 v0 = __half22float2(hp[0]);
            float2 v1 = __half22float2(hp[1]);
            float2 v2 = __half22float2(hp[2]);
            float2 v3 = __half22float2(hp[3]);
            acc = fmaf(v0.x, wres[8*q+0], acc);
            acc = fmaf(v0.y, wres[8*q+1], acc);
            acc = fmaf(v1.x, wres[8*q+2], acc);
            acc = fmaf(v1.y, wres[8*q+3], acc);
            acc = fmaf(v2.x, wres[8*q+4], acc);
            acc = fmaf(v2.y, wres[8*q+5], acc);
            acc = fmaf(v3.x, wres[8*q+6], acc);
            acc = fmaf(v3.y, wres[8*q+7], acc);
        }
        ((__half*)xe)[(size_t)t * HD + lane] = __float2half(acc);   // coalesced 128B
        float t0 = acc * as_, t1 = acc * ad_;
        if (H == 8) {
            #pragma unroll
            for (int m = 1; m < 8; m <<= 1) {
                t0 += __shfl_xor(t0, m, 64);
                t1 += __shfl_xor(t1, m, 64);
            }
            if ((lane & 7) == 0) {
                es[t * 8 + (lane >> 3)] = t0;
                ed[t * 8 + (lane >> 3)] = t1;
            }
        } else {
            #pragma unroll
            for (int m = 1; m < 64; m <<= 1) {
                t0 += __shfl_xor(t0, m, 64);
                t1 += __shfl_xor(t1, m, 64);
            }
            if (lane == 0) { es[t] = t0; ed[t] = t1; }
        }
    }
}

// layer 0: proj fused in. h row computed per-lane, broadcast via fp16 LDS row.
__global__ __launch_bounds__(256, 4)
void fused0_kernel(const float* __restrict__ x, const float* __restrict__ pw,
                   const float* __restrict__ pb, const float* __restrict__ w,
                   const float* __restrict__ asrc, const float* __restrict__ adst,
                   float* __restrict__ xe, float* __restrict__ es, float* __restrict__ ed) {
    __shared__ __half tileh[GT * HD];   // 8KB
    __shared__ float xt[S * GT];
    int base = blockIdx.x * GT;
    for (int i = threadIdx.x; i < S * GT; i += 256) {
        int s = i >> 6, nl = i & 63;
        int t = base + nl, bb = t / N, n = t - bb * N;
        xt[i] = x[(bb * S + s) * N + n];          // coalesced per s-segment
    }
    int lane = threadIdx.x & 63;
    float wres[HD];
    #pragma unroll
    for (int c = 0; c < HD; ++c) wres[c] = w[c * HD + lane];
    float pwres[S];
    #pragma unroll
    for (int s = 0; s < S; ++s) pwres[s] = pw[s * HD + lane];
    float pbv = pb[lane];
    float as_ = asrc[lane], ad_ = adst[lane];
    __syncthreads();
    int wvid = threadIdx.x >> 6;
    // phase A: this wave's 16 h-rows (lane = channel), written to tile fp16
    for (int j = wvid * 16; j < wvid * 16 + 16; ++j) {
        float hl = pbv;
        #pragma unroll
        for (int s = 0; s < S; ++s)
            hl = fmaf(xt[s * GT + j], pwres[s], hl);         // broadcast read
        tileh[j * HD + lane] = __float2half(hl);             // own wave's row
    }
    // phase B: gemm + attn (reads only this wave's rows -> no barrier needed)
    for (int j = wvid * 16; j < wvid * 16 + 16; ++j) {
        int t = base + j;
        float acc = 0.f;
        #pragma unroll
        for (int q = 0; q < 8; ++q) {
            float4 raw = ((const float4*)tileh)[j * 8 + q];
            const __half2* hp = (const __half2*)&raw;
            float2 v0 = __half22float2(hp[0]);
            float2 v1 = __half22float2(hp[1]);
            float2 v2 = __half22float2(hp[2]);
            float2 v3 = __half22float2(hp[3]);
            acc = fmaf(v0.x, wres[8*q+0], acc);
            acc = fmaf(v0.y, wres[8*q+1], acc);
            acc = fmaf(v1.x, wres[8*q+2], acc);
            acc = fmaf(v1.y, wres[8*q+3], acc);
            acc = fmaf(v2.x, wres[8*q+4], acc);
            acc = fmaf(v2.y, wres[8*q+5], acc);
            acc = fmaf(v3.x, wres[8*q+6], acc);
            acc = fmaf(v3.y, wres[8*q+7], acc);
        }
        ((__half*)xe)[(size_t)t * HD + lane] = __float2half(acc);
        float t0 = acc * as_, t1 = acc * ad_;
        #pragma unroll
        for (int m = 1; m < 8; m <<= 1) {
            t0 += __shfl_xor(t0, m, 64);
            t1 += __shfl_xor(t1, m, 64);
        }
        if ((lane & 7) == 0) {
            es[t * 8 + (lane >> 3)] = t0;
            ed[t * 8 + (lane >> 3)] = t1;
        }
    }
}

// ------- fused aggregation v17: 8 groups x 8 lanes — 2x edges in flight -----
// Confirmed −16us (R12). 32 edges in flight/wave ≈ mean degree: MLP saturated.
template<int H, bool DO_ELU, bool OUT_HALF>
__global__ __launch_bounds__(256, 8)
void agg_kernel(const float* __restrict__ xe, const float* __restrict__ es,
                const float* __restrict__ ed, const int* __restrict__ cnt,
                const int* __restrict__ perm, const float* __restrict__ bias,
                float* __restrict__ hout) {
    int g = blockIdx.x;                       // 20000 blocks, multiple of 8
    int bb   = (g & 7) >> 1;                  // batch from XCD pair
    int idx  = (g >> 3) * 2 + (g & 1);        // 0..4999 within batch
    int node = idx * 4 + (threadIdx.x >> 6);  // < 20000
    int lane  = threadIdx.x & 63;
    int group = lane >> 3;                    // 0..7: owns an edge
    int c8    = lane & 7;                     // head (H=8) / channel octet
    int deg = cnt[node];
    int baseE = node * CAP;
    int h = (H == 8) ? c8 : 0;
    const float*  es_b = es + bb * (N * H);
    const __half* xeh  = (const __half*)xe + (size_t)bb * N * HD;
    float edv = ed[(bb * N + node) * H + h];
    float acc[8] = {0.f,0.f,0.f,0.f,0.f,0.f,0.f,0.f};
    float ssum = 0.f;
    #pragma unroll 4
    for (int jb = 0; jb < deg; jb += 8) {
        int j = jb + group;
        bool valid = (j < deg);
        int src = perm[baseE + (valid ? j : 0)];     // slot 0 always exists
        float e = es_b[src * H + h] + edv;
        e = fmaxf(e, 0.2f * e);                      // leaky_relu(0.2)
        float p = valid ? __expf(e) : 0.f;
        ssum += p;
        float4 raw = *(const float4*)(xeh + (size_t)src * HD + c8 * 8);  // 16B
        const __half2* hp2 = (const __half2*)&raw;
        float2 v0 = __half22float2(hp2[0]);
        float2 v1 = __half22float2(hp2[1]);
        float2 v2 = __half22float2(hp2[2]);
        float2 v3 = __half22float2(hp2[3]);
        acc[0] = fmaf(p, v0.x, acc[0]);
        acc[1] = fmaf(p, v0.y, acc[1]);
        acc[2] = fmaf(p, v1.x, acc[2]);
        acc[3] = fmaf(p, v1.y, acc[3]);
        acc[4] = fmaf(p, v2.x, acc[4]);
        acc[5] = fmaf(p, v2.y, acc[5]);
        acc[6] = fmaf(p, v3.x, acc[6]);
        acc[7] = fmaf(p, v3.y, acc[7]);
    }
    #pragma unroll
    for (int m = 8; m < 64; m <<= 1) {
        #pragma unroll
        for (int k = 0; k < 8; ++k) acc[k] += __shfl_xor(acc[k], m, 64);
        ssum += __shfl_xor(ssum, m, 64);
    }
    if (lane < 8) {                     // lane = c8: owns channels c8*8..+7
        float inv = 1.f / ssum;
        const float4* b4 = (const float4*)bias;
        float4 b0 = b4[c8 * 2 + 0], b1 = b4[c8 * 2 + 1];
        float r[8];
        r[0] = acc[0] * inv + b0.x; r[1] = acc[1] * inv + b0.y;
        r[2] = acc[2] * inv + b0.z; r[3] = acc[3] * inv + b0.w;
        r[4] = acc[4] * inv + b1.x; r[5] = acc[5] * inv + b1.y;
        r[6] = acc[6] * inv + b1.z; r[7] = acc[7] * inv + b1.w;
        if (DO_ELU) {
            #pragma unroll
            for (int k = 0; k < 8; ++k)
                r[k] = (r[k] > 0.f) ? r[k] : expm1f(r[k]);
        }
        if (OUT_HALF) {
            union { __half2 h2[4]; float4 f4; } u;
            u.h2[0] = __floats2half2_rn(r[0], r[1]);
            u.h2[1] = __floats2half2_rn(r[2], r[3]);
            u.h2[2] = __floats2half2_rn(r[4], r[5]);
            u.h2[3] = __floats2half2_rn(r[6], r[7]);
            ((float4*)hout)[(size_t)(bb * N + node) * 8 + c8] = u.f4;   // 16B
        } else {
            float4 lo = {r[0], r[1], r[2], r[3]};
            float4 hi = {r[4], r[5], r[6], r[7]};
            float4* o4 = (float4*)hout + (size_t)(bb * N + node) * 16 + c8 * 2;
            o4[0] = lo;
            o4[1] = hi;
        }
    }
}

// ======== conv v20 = v18 body (REVERT from v19) + j-loop unroll 4 ===========
// v19 (row-reuse) regressed 59.7->65.8: clean health but Occ 35->28 (VGPR 56)
// and each row's full dwordx16 s_load gates 3 serial FMA+LDS-RMW chains —
// explicit reuse lost to v18's load/compute interleave. REVERT to v18 exact.
// Single delta: j-loop unroll 2 -> 4. v18's SGPR 64 showed ~1 row buffered;
// budget allows ~2 (32 SGPR/row). Deeper unroll gives the scheduler more
// independent (dt,j) iterations to overlap s_loads across. Health: WRITE
// 937KB, FETCH ~10.8MB; watch SGPR (rise = deeper pipeline; 64 = saturated).
constexpr int CVN = 16;                 // nodes per wave
__global__ __launch_bounds__(128, 2)
void conv_out_kernel(const float* __restrict__ h, const float* __restrict__ cwD,
                     const float* __restrict__ cb, const float* __restrict__ ow,
                     const float* __restrict__ ob, float* __restrict__ out) {
    __shared__ float part[2 * CVN * HD];   // 8KB, wave-private halves
    int bb = blockIdx.y;
    int wvid = __builtin_amdgcn_readfirstlane(threadIdx.x >> 6);  // SGPR: 0..1
    int base = blockIdx.x * (2 * CVN) + wvid * CVN;   // scalar; N = 625*32
    int lane = threadIdx.x & 63;           // = output channel o
    float* wp = part + wvid * (CVN * HD);  // this wave's 4KB slice (scalar base)
    const __half* hb = (const __half*)h;   // fp16 rows from agg2
    float cbv = cb[lane];
    float ow0 = ow[lane * 3 + 0], ow1 = ow[lane * 3 + 1], ow2 = ow[lane * 3 + 2];
    float ob0 = ob[0], ob1 = ob[1], ob2 = ob[2];
    #pragma unroll
    for (int j = 0; j < CVN; ++j) wp[j * HD + lane] = cbv;
    #pragma unroll 1
    for (int dt = 0; dt < 3; ++dt) {
        float wres[HD];                 // cwD[dt][c][lane], coalesced VMEM
        #pragma unroll
        for (int c = 0; c < HD; ++c) wres[c] = cwD[dt * (HD * HD) + c * HD + lane];
        #pragma unroll 4
        for (int j = 0; j < CVN; ++j) {
            int m = base + j + dt - 1;
            if (m >= 0 && m < N) {      // uniform branch (s_cbranch)
                const unsigned int* hpu =
                    (const unsigned int*)(hb + ((size_t)bb * N + m) * HD); // scalar
                float a = 0.f;
                #pragma unroll
                for (int c2 = 0; c2 < 32; ++c2) {
                    unsigned int wbits = hpu[c2];            // s_load (32 dwords/row)
                    __half2 h2 = *(const __half2*)&wbits;
                    float2 vf = __half22float2(h2);
                    a = fmaf(vf.x, wres[2 * c2 + 0], a);
                    a = fmaf(vf.y, wres[2 * c2 + 1], a);
                }
                wp[j * HD + lane] += a;             // wave-local LDS RMW
            }
        }
    }
    // epilogue: relu + 64->3 via butterfly
    #pragma unroll 1
    for (int j = 0; j < CVN; ++j) {
        float v = fmaxf(wp[j * HD + lane], 0.f);
        float t0 = v * ow0, t1 = v * ow1, t2 = v * ow2;
        #pragma unroll
        for (int m = 1; m < 64; m <<= 1) {
            t0 += __shfl_xor(t0, m, 64);
            t1 += __shfl_xor(t1, m, 64);
            t2 += __shfl_xor(t2, m, 64);
        }
        int n = base + j;               // always < N (625*32 = 20000)
        if (lane < 3) {
            float r = (lane == 0) ? t0 + ob0 : (lane == 1) ? t1 + ob1 : t2 + ob2;
            out[(size_t)bb * 3 * N + lane * N + n] = r;
        }
    }
}

extern "C" void kernel_launch(void* const* d_in, const int* in_sizes, int n_in,
                              void* d_out, int out_size, void* d_ws, size_t ws_size,
                              hipStream_t stream) {
    const float* x      = (const float*)d_in[0];
    const int*   ei     = (const int*)  d_in[1];
    const float* proj_w = (const float*)d_in[2];
    const float* proj_b = (const float*)d_in[3];
    const float* g_w [3] = {(const float*)d_in[4], (const float*)d_in[8],  (const float*)d_in[12]};
    const float* g_as[3] = {(const float*)d_in[5], (const float*)d_in[9],  (const float*)d_in[13]};
    const float* g_ad[3] = {(const float*)d_in[6], (const float*)d_in[10], (const float*)d_in[14]};
    const float* g_b [3] = {(const float*)d_in[7], (const float*)d_in[11], (const float*)d_in[15]};
    const float* conv_w = (const float*)d_in[16];
    const float* conv_b = (const float*)d_in[17];
    const float* out_w  = (const float*)d_in[18];
    const float* out_b  = (const float*)d_in[19];
    float* out = (float*)d_out;

    // workspace layout (fp32-sized regions; bufX = fp16 xe; bufA = fp16
    // hidden state everywhere now, incl. conv input)
    float* bufA = (float*)d_ws;                      // BN*HD
    float* bufX = bufA + (size_t)BN * HD;            // BN*HD
    float* es   = bufX + (size_t)BN * HD;            // BN*8 (max H)
    float* ed   = es   + (size_t)BN * 8;             // BN*8
    int* cnt  = (int*)(ed + (size_t)BN * 8);         // N
    int* perm = cnt + N;                             // N*CAP
    float* cwD = (float*)(perm + (size_t)N * CAP);   // 3*64*64

    const int TB = 256;
    const int gE = (EL + TB - 1) / TB;

    // CSR build: memset + single scatter (padded buckets, no scan)
    hipMemsetAsync(cnt, 0, N * sizeof(int), stream);
    scatter_kernel<<<gE, TB, 0, stream>>>(ei, cnt, perm);

    // conv weight transpose to [dt][c][o]
    tw_kernel<<<(HD * HD * 3 + TB - 1) / TB, TB, 0, stream>>>(conv_w, cwD);

    // layer 0: proj + gemm + attn fused (reads x directly)
    fused0_kernel<<<BN / GT, TB, 0, stream>>>(x, proj_w, proj_b, g_w[0], g_as[0], g_ad[0],
                                              bufX, es, ed);
    agg_kernel<8, true, true><<<BN / 4, TB, 0, stream>>>(bufX, es, ed, cnt, perm, g_b[0], bufA);

    // layer 1 (H=8) + ELU; hin fp16
    gemm_attn_kernel<8><<<BN / GT, TB, 0, stream>>>(bufA, g_w[1], g_as[1], g_ad[1], bufX, es, ed);
    agg_kernel<8, true, true><<<BN / 4, TB, 0, stream>>>(bufX, es, ed, cnt, perm, g_b[1], bufA);

    // layer 2 (H=1), no ELU; hin fp16, hout fp16 (conv reads fp16 rows)
    gemm_attn_kernel<1><<<BN / GT, TB, 0, stream>>>(bufA, g_w[2], g_as[2], g_ad[2], bufX, es, ed);
    agg_kernel<1, false, true><<<BN / 4, TB, 0, stream>>>(bufX, es, ed, cnt, perm, g_b[2], bufA);

    // conv1d(k=3) + relu + final projection, writes [B,3,N]
    conv_out_kernel<<<dim3(N / (2 * CVN), B), 128, 0, stream>>>(bufA, cwD, conv_b, out_w, out_b, out);
}